// Round 8
// baseline (1348.202 us; speedup 1.0000x reference)
//
#include <hip/hip_runtime.h>
#include <hip/hip_bf16.h>

#define NGROUPS 8   // L=2 labels * S=4 sessions
#define DIM 128
// per-replica layout (floats): [0,1024) sums[8][128], [1024,2048) wsums[8][128], [2048,2056) counts[8]
#define WS_FLOATS 2056
#define NREP 16     // global atomic replicas to cut same-address chains

// x + dpp(x): one step of a VALU-only wave reduction (no LDS pipe)
template <int CTRL>
__device__ __forceinline__ float dpp_add(float x) {
    int s = __builtin_amdgcn_update_dpp(0, __float_as_int(x), CTRL, 0xF, 0xF, true);
    return x + __int_as_float(s);
}

// 64-lane sum; lane 63 ends with the total. 1/max(sqrt,eps) via rsq+cap,
// broadcast to an SGPR with readlane.
__device__ __forceinline__ float wave_rnorm(float ss) {
    float r = ss;
    r = dpp_add<0x111>(r);  // row_shr:1
    r = dpp_add<0x112>(r);  // row_shr:2
    r = dpp_add<0x114>(r);  // row_shr:4
    r = dpp_add<0x118>(r);  // row_shr:8
    r = dpp_add<0x142>(r);  // row_bcast:15
    r = dpp_add<0x143>(r);  // row_bcast:31  -> lane 63 holds the total
    float inv = fminf(__builtin_amdgcn_rsqf(r), 1e8f);  // 1e8 == 1/eps cap
    return __int_as_float(__builtin_amdgcn_readlane(__float_as_int(inv), 63));
}

// 1024 threads (16 waves), 2 blocks/CU -> 8 waves/SIMD; VGPR budget 64.
__global__ __launch_bounds__(1024, 8)
void csca_accum_kernel(const float2* __restrict__ feat2,
                       const int* __restrict__ labels,
                       const int* __restrict__ sessions,
                       float* __restrict__ gws, int B) {
    __shared__ float s_all[WS_FLOATS];
    for (int i = threadIdx.x; i < WS_FLOATS; i += 1024) s_all[i] = 0.0f;
    __syncthreads();

    const int lane = threadIdx.x & 63;
    const int wid = blockIdx.x * 16 + (threadIdx.x >> 6);  // wave id
    const int NW = gridDim.x * 16;                         // total waves

    const int4* lab4 = (const int4*)labels;
    const int4* ses4 = (const int4*)sessions;

    int cntq[NGROUPS];
#pragma unroll
    for (int q = 0; q < NGROUPS; ++q) cntq[q] = 0;

    const int fI = B / (NW * 4);   // 32 for B=1M, 512x1024 grid
    for (int it = 0; it < fI; ++it) {
        const int r0 = (it * NW + wid) * 4;   // wave-uniform, %4==0
        int4 lb = lab4[r0 >> 2];              // scalar x4 loads
        int4 se = ses4[r0 >> 2];
        float2 v[4];
#pragma unroll
        for (int j = 0; j < 4; ++j)
            v[j] = feat2[(size_t)(r0 + j) * 64 + lane];   // 512B/wave, coalesced

        // 4 interleaved VALU-only reduce chains
        float r0s = fmaf(v[0].x, v[0].x, v[0].y * v[0].y);
        float r1s = fmaf(v[1].x, v[1].x, v[1].y * v[1].y);
        float r2s = fmaf(v[2].x, v[2].x, v[2].y * v[2].y);
        float r3s = fmaf(v[3].x, v[3].x, v[3].y * v[3].y);
        float rn[4];
        rn[0] = wave_rnorm(r0s);
        rn[1] = wave_rnorm(r1s);
        rn[2] = wave_rnorm(r2s);
        rn[3] = wave_rnorm(r3s);

        int gv[4];
        gv[0] = lb.x * 4 + se.x;
        gv[1] = lb.y * 4 + se.y;
        gv[2] = lb.z * 4 + se.z;
        gv[3] = lb.w * 4 + se.w;

#pragma unroll
        for (int j = 0; j < 4; ++j) {
            const int g = gv[j];                       // wave-uniform (SGPR)
            float* base = &s_all[g * DIM + 2 * lane];  // 1 VALU addr; rest via offset:
            atomicAdd(base,        v[j].x);            // ds_add_f32
            atomicAdd(base + 1,    v[j].y);
            atomicAdd(base + 1024, rn[j] * v[j].x);
            atomicAdd(base + 1025, rn[j] * v[j].y);
#pragma unroll
            for (int q = 0; q < NGROUPS; ++q)          // SALU compare chain
                cntq[q] += (g == q) ? 1 : 0;
        }
    }

    // tail rows (empty when B % (NW*4) == 0; kept for generality)
    for (int row = fI * NW * 4 + wid; row < B; row += NW) {
        float2 vv = feat2[(size_t)row * 64 + lane];
        int g = __builtin_amdgcn_readfirstlane(labels[row] * 4 + sessions[row]);
        float ss = fmaf(vv.x, vv.x, vv.y * vv.y);
        float rn = wave_rnorm(ss);
        float* base = &s_all[g * DIM + 2 * lane];
        atomicAdd(base,        vv.x);
        atomicAdd(base + 1,    vv.y);
        atomicAdd(base + 1024, rn * vv.x);
        atomicAdd(base + 1025, rn * vv.y);
#pragma unroll
        for (int q = 0; q < NGROUPS; ++q) cntq[q] += (g == q) ? 1 : 0;
    }

    // per-wave counts -> LDS once
    if (lane == 0) {
#pragma unroll
        for (int q = 0; q < NGROUPS; ++q)
            atomicAdd(&s_all[2048 + q], (float)cntq[q]);
    }
    __syncthreads();

    float* rep = gws + (size_t)(blockIdx.x & (NREP - 1)) * WS_FLOATS;
    for (int i = threadIdx.x; i < WS_FLOATS; i += 1024) atomicAdd(&rep[i], s_all[i]);
}

__global__ __launch_bounds__(256)
void csca_finalize_kernel(const float* __restrict__ gws, float* __restrict__ out, float invB) {
    __shared__ float red[WS_FLOATS];
    for (int i = threadIdx.x; i < WS_FLOATS; i += 256) {
        float s = 0.0f;
#pragma unroll
        for (int r = 0; r < NREP; ++r) s += gws[(size_t)r * WS_FLOATS + i];
        red[i] = s;
    }
    __syncthreads();

    if (threadIdx.x < 64) {
        const int lane = threadIdx.x;
        const float* sums  = red;
        const float* wsums = red + 1024;
        const float* cnts  = red + 2048;
        __shared__ float c_lds[NGROUPS][DIM];
        float cnorm2[NGROUPS];
        float cos_sum = 0.0f;

#pragma unroll
        for (int g = 0; g < NGROUPS; ++g) {
            float invc = 1.0f / cnts[g];
            float c0 = sums[g * DIM + lane] * invc;
            float c1 = sums[g * DIM + 64 + lane] * invc;
            c_lds[g][lane] = c0;
            c_lds[g][64 + lane] = c1;
            float w0 = wsums[g * DIM + lane];
            float w1 = wsums[g * DIM + 64 + lane];
            float pcc = c0 * c0 + c1 * c1;
            float pwc = w0 * c0 + w1 * c1;
#pragma unroll
            for (int m = 1; m < 64; m <<= 1) {
                pcc += __shfl_xor(pcc, m);
                pwc += __shfl_xor(pwc, m);
            }
            cnorm2[g] = pcc;
            cos_sum += pwc / fmaxf(sqrtf(pcc), 1e-8f);
        }
        float center_loss = 1.0f - cos_sum * invB;

        float align = 0.0f;
#pragma unroll
        for (int y = 0; y < 2; ++y) {
            float p0 = 0.0f, p1 = 0.0f;
#pragma unroll
            for (int s = 0; s < 4; ++s) {
                p0 += c_lds[4 * y + s][lane];
                p1 += c_lds[4 * y + s][64 + lane];
            }
            p0 *= 0.25f; p1 *= 0.25f;
            float ppp = p0 * p0 + p1 * p1;
#pragma unroll
            for (int m = 1; m < 64; m <<= 1) ppp += __shfl_xor(ppp, m);
            float pn = fmaxf(sqrtf(ppp), 1e-8f);
            float pc = 0.0f;
#pragma unroll
            for (int s = 0; s < 4; ++s) {
                float d = c_lds[4 * y + s][lane] * p0 + c_lds[4 * y + s][64 + lane] * p1;
#pragma unroll
                for (int m = 1; m < 64; m <<= 1) d += __shfl_xor(d, m);
                float cs = d / (fmaxf(sqrtf(cnorm2[4 * y + s]), 1e-8f) * pn);
                pc += 1.0f - cs;
            }
            align = (align + pc) * 0.25f;  // running /S division, faithful to reference
        }

        if (lane == 0) {
            out[0] = center_loss + align;
            out[1] = center_loss;
            out[2] = align;
        }
    }
}

extern "C" void kernel_launch(void* const* d_in, const int* in_sizes, int n_in,
                              void* d_out, int out_size, void* d_ws, size_t ws_size,
                              hipStream_t stream) {
    const float* feat = (const float*)d_in[0];
    const int* labels = (const int*)d_in[1];
    const int* sessions = (const int*)d_in[2];
    const int B = in_sizes[1];          // 1048576 (features are B x 128)
    float* gws = (float*)d_ws;

    hipMemsetAsync(gws, 0, (size_t)NREP * WS_FLOATS * sizeof(float), stream);

    csca_accum_kernel<<<512, 1024, 0, stream>>>((const float2*)feat, labels, sessions, gws, B);
    csca_finalize_kernel<<<1, 256, 0, stream>>>(gws, (float*)d_out, 1.0f / (float)B);
}

// Round 9
// 183.779 us; speedup vs baseline: 7.3360x; 7.3360x over previous
//
#include <hip/hip_runtime.h>
#include <hip/hip_bf16.h>

#define NGROUPS 8   // L=2 labels * S=4 sessions
#define DIM 128
// per-replica layout (floats): [0,1024) sums[8][128], [1024,2048) wsums[8][128], [2048,2056) counts[8]
#define WS_FLOATS 2056
#define NREP 16     // global atomic replicas to cut same-address chains

// x + dpp(x): one step of a VALU-only wave reduction (no LDS pipe)
template <int CTRL>
__device__ __forceinline__ float dpp_add(float x) {
    int s = __builtin_amdgcn_update_dpp(0, __float_as_int(x), CTRL, 0xF, 0xF, true);
    return x + __int_as_float(s);
}

// 64-lane sum; lane 63 ends with the total. 1/max(sqrt,eps) via rsq + cap,
// broadcast to an SGPR with readlane.
__device__ __forceinline__ float wave_rnorm(float ss) {
    float r = ss;
    r = dpp_add<0x111>(r);  // row_shr:1
    r = dpp_add<0x112>(r);  // row_shr:2
    r = dpp_add<0x114>(r);  // row_shr:4
    r = dpp_add<0x118>(r);  // row_shr:8
    r = dpp_add<0x142>(r);  // row_bcast:15
    r = dpp_add<0x143>(r);  // row_bcast:31  -> lane 63 holds the total
    float inv = fminf(__builtin_amdgcn_rsqf(r), 1e8f);  // 1e8 == 1/eps cap
    return __int_as_float(__builtin_amdgcn_readlane(__float_as_int(inv), 63));
}

// 256 threads, 8 waves/SIMD (VGPR cap 64): rider-level occupancy.
// Accumulators 32 VGPR; masks are SGPR floats via s_cselect (g is scalar).
__global__ __launch_bounds__(256, 8)
void csca_accum_kernel(const float2* __restrict__ feat2,
                       const int* __restrict__ labels,
                       const int* __restrict__ sessions,
                       float* __restrict__ gws, int B) {
    __shared__ float s_all[WS_FLOATS];
    for (int i = threadIdx.x; i < WS_FLOATS; i += 256) s_all[i] = 0.0f;
    __syncthreads();

    const int lane = threadIdx.x & 63;
    const int wid = __builtin_amdgcn_readfirstlane(blockIdx.x * 4 + (threadIdx.x >> 6));
    const int NW = gridDim.x * 4;   // total waves (8192)

    const int2* lab2 = (const int2*)labels;
    const int2* ses2 = (const int2*)sessions;

    float sa[NGROUPS][2], wa[NGROUPS][2];
    int cnt[NGROUPS];               // scalar (g comparisons are uniform)
#pragma unroll
    for (int q = 0; q < NGROUPS; ++q) {
        sa[q][0] = 0.0f; sa[q][1] = 0.0f; wa[q][0] = 0.0f; wa[q][1] = 0.0f;
        cnt[q] = 0;
    }

    const int fI = B / (NW * 2);    // 64 for B=1M
    for (int it = 0; it < fI; ++it) {
        const int r0 = (it * NW + wid) * 2;       // uniform, even
        int2 lb = lab2[r0 >> 1];                  // s_load_dwordx2
        int2 se = ses2[r0 >> 1];
        float2 v0 = feat2[(size_t)r0 * 64 + lane];        // 512B/wave, coalesced
        float2 v1 = feat2[(size_t)(r0 + 1) * 64 + lane];

        float ss0 = fmaf(v0.x, v0.x, v0.y * v0.y);
        float ss1 = fmaf(v1.x, v1.x, v1.y * v1.y);
        float rn0 = wave_rnorm(ss0);              // SGPR
        float rn1 = wave_rnorm(ss1);

        const int g0 = lb.x * 4 + se.x;           // SGPR
        const int g1 = lb.y * 4 + se.y;

#pragma unroll
        for (int q = 0; q < NGROUPS; ++q) {
            // SALU s_cselect masks; each v_fmac reads exactly one SGPR
            float m0 = (g0 == q) ? 1.0f : 0.0f;
            float w0 = (g0 == q) ? rn0 : 0.0f;
            float m1 = (g1 == q) ? 1.0f : 0.0f;
            float w1 = (g1 == q) ? rn1 : 0.0f;
            sa[q][0] = fmaf(m0, v0.x, sa[q][0]);
            sa[q][1] = fmaf(m0, v0.y, sa[q][1]);
            wa[q][0] = fmaf(w0, v0.x, wa[q][0]);
            wa[q][1] = fmaf(w0, v0.y, wa[q][1]);
            sa[q][0] = fmaf(m1, v1.x, sa[q][0]);
            sa[q][1] = fmaf(m1, v1.y, sa[q][1]);
            wa[q][0] = fmaf(w1, v1.x, wa[q][0]);
            wa[q][1] = fmaf(w1, v1.y, wa[q][1]);
            cnt[q] += (g0 == q) ? 1 : 0;
            cnt[q] += (g1 == q) ? 1 : 0;
        }
    }

    // tail rows (empty when B % (NW*2) == 0; kept for generality)
    for (int row = fI * NW * 2 + wid; row < B; row += NW) {
        float2 v = feat2[(size_t)row * 64 + lane];
        int g = __builtin_amdgcn_readfirstlane(labels[row] * 4 + sessions[row]);
        float ss = fmaf(v.x, v.x, v.y * v.y);
        float rn = wave_rnorm(ss);
#pragma unroll
        for (int q = 0; q < NGROUPS; ++q) {
            float m = (g == q) ? 1.0f : 0.0f;
            float w = (g == q) ? rn : 0.0f;
            sa[q][0] = fmaf(m, v.x, sa[q][0]);
            sa[q][1] = fmaf(m, v.y, sa[q][1]);
            wa[q][0] = fmaf(w, v.x, wa[q][0]);
            wa[q][1] = fmaf(w, v.y, wa[q][1]);
            cnt[q] += (g == q) ? 1 : 0;
        }
    }

    // end-of-kernel block reduction (LDS atomics OK here: once, not per-row)
#pragma unroll
    for (int q = 0; q < NGROUPS; ++q) {
        atomicAdd(&s_all[q * DIM + 2 * lane],            sa[q][0]);
        atomicAdd(&s_all[q * DIM + 2 * lane + 1],        sa[q][1]);
        atomicAdd(&s_all[1024 + q * DIM + 2 * lane],     wa[q][0]);
        atomicAdd(&s_all[1024 + q * DIM + 2 * lane + 1], wa[q][1]);
    }
    if (lane == 0) {
#pragma unroll
        for (int q = 0; q < NGROUPS; ++q)
            atomicAdd(&s_all[2048 + q], (float)cnt[q]);
    }
    __syncthreads();

    float* rep = gws + (size_t)(blockIdx.x & (NREP - 1)) * WS_FLOATS;
    for (int i = threadIdx.x; i < WS_FLOATS; i += 256) atomicAdd(&rep[i], s_all[i]);
}

__global__ __launch_bounds__(256)
void csca_finalize_kernel(const float* __restrict__ gws, float* __restrict__ out, float invB) {
    __shared__ float red[WS_FLOATS];
    for (int i = threadIdx.x; i < WS_FLOATS; i += 256) {
        float s = 0.0f;
#pragma unroll
        for (int r = 0; r < NREP; ++r) s += gws[(size_t)r * WS_FLOATS + i];
        red[i] = s;
    }
    __syncthreads();

    if (threadIdx.x < 64) {
        const int lane = threadIdx.x;
        const float* sums  = red;
        const float* wsums = red + 1024;
        const float* cnts  = red + 2048;
        __shared__ float c_lds[NGROUPS][DIM];
        float cnorm2[NGROUPS];
        float cos_sum = 0.0f;

#pragma unroll
        for (int g = 0; g < NGROUPS; ++g) {
            float invc = 1.0f / cnts[g];
            float c0 = sums[g * DIM + lane] * invc;
            float c1 = sums[g * DIM + 64 + lane] * invc;
            c_lds[g][lane] = c0;
            c_lds[g][64 + lane] = c1;
            float w0 = wsums[g * DIM + lane];
            float w1 = wsums[g * DIM + 64 + lane];
            float pcc = c0 * c0 + c1 * c1;
            float pwc = w0 * c0 + w1 * c1;
#pragma unroll
            for (int m = 1; m < 64; m <<= 1) {
                pcc += __shfl_xor(pcc, m);
                pwc += __shfl_xor(pwc, m);
            }
            cnorm2[g] = pcc;
            cos_sum += pwc / fmaxf(sqrtf(pcc), 1e-8f);
        }
        float center_loss = 1.0f - cos_sum * invB;

        float align = 0.0f;
#pragma unroll
        for (int y = 0; y < 2; ++y) {
            float p0 = 0.0f, p1 = 0.0f;
#pragma unroll
            for (int s = 0; s < 4; ++s) {
                p0 += c_lds[4 * y + s][lane];
                p1 += c_lds[4 * y + s][64 + lane];
            }
            p0 *= 0.25f; p1 *= 0.25f;
            float ppp = p0 * p0 + p1 * p1;
#pragma unroll
            for (int m = 1; m < 64; m <<= 1) ppp += __shfl_xor(ppp, m);
            float pn = fmaxf(sqrtf(ppp), 1e-8f);
            float pc = 0.0f;
#pragma unroll
            for (int s = 0; s < 4; ++s) {
                float d = c_lds[4 * y + s][lane] * p0 + c_lds[4 * y + s][64 + lane] * p1;
#pragma unroll
                for (int m = 1; m < 64; m <<= 1) d += __shfl_xor(d, m);
                float cs = d / (fmaxf(sqrtf(cnorm2[4 * y + s]), 1e-8f) * pn);
                pc += 1.0f - cs;
            }
            align = (align + pc) * 0.25f;  // running /S division, faithful to reference
        }

        if (lane == 0) {
            out[0] = center_loss + align;
            out[1] = center_loss;
            out[2] = align;
        }
    }
}

extern "C" void kernel_launch(void* const* d_in, const int* in_sizes, int n_in,
                              void* d_out, int out_size, void* d_ws, size_t ws_size,
                              hipStream_t stream) {
    const float* feat = (const float*)d_in[0];
    const int* labels = (const int*)d_in[1];
    const int* sessions = (const int*)d_in[2];
    const int B = in_sizes[1];          // 1048576 (features are B x 128)
    float* gws = (float*)d_ws;

    hipMemsetAsync(gws, 0, (size_t)NREP * WS_FLOATS * sizeof(float), stream);

    csca_accum_kernel<<<2048, 256, 0, stream>>>((const float2*)feat, labels, sessions, gws, B);
    csca_finalize_kernel<<<1, 256, 0, stream>>>(gws, (float*)d_out, 1.0f / (float)B);
}